// Round 1
// baseline (123.618 us; speedup 1.0000x reference)
//
#include <hip/hip_runtime.h>

// predict/target: fp32, shape (64, 3, 17, 4096)
// loss = sum((t-p)^2 * w[c]) / (bs*actionlen*seqlen),  w = {1, 1, 75825}
//
// Stage 1: grid-stride float4 reduction -> per-block partials in d_ws
// Stage 2: single block reduces partials, scales, writes d_out[0]

#define BLOCK_SIZE 256
#define NUM_BLOCKS 2048
#define VEC_PER_CHAN 17408   // (17*4096)/4 : float4-groups per channel segment
#define W2 75825.0f          // MAXLEN

__global__ __launch_bounds__(BLOCK_SIZE) void pm_mse_partial(
    const float4* __restrict__ p, const float4* __restrict__ t,
    float* __restrict__ partial, int n4) {
    float acc = 0.0f;
    const int stride = gridDim.x * blockDim.x;
    for (int i = blockIdx.x * blockDim.x + threadIdx.x; i < n4; i += stride) {
        float4 a = p[i];
        float4 b = t[i];
        float dx = b.x - a.x;
        float dy = b.y - a.y;
        float dz = b.z - a.z;
        float dw = b.w - a.w;
        float s = dx * dx + dy * dy + dz * dz + dw * dw;
        // channel index: vec4 groups never straddle a channel boundary
        int c = (i / VEC_PER_CHAN) % 3;
        acc += (c == 2) ? s * W2 : s;
    }
    // wave (64-lane) shuffle reduction
    for (int off = 32; off > 0; off >>= 1)
        acc += __shfl_down(acc, off, 64);
    __shared__ float smem[BLOCK_SIZE / 64];
    const int lane = threadIdx.x & 63;
    const int wid = threadIdx.x >> 6;
    if (lane == 0) smem[wid] = acc;
    __syncthreads();
    if (threadIdx.x == 0) {
        float s = 0.0f;
        #pragma unroll
        for (int w = 0; w < BLOCK_SIZE / 64; ++w) s += smem[w];
        partial[blockIdx.x] = s;
    }
}

__global__ __launch_bounds__(BLOCK_SIZE) void pm_mse_final(
    const float* __restrict__ partial, int nblocks, float* __restrict__ out,
    float scale) {
    double acc = 0.0;
    for (int i = threadIdx.x; i < nblocks; i += blockDim.x)
        acc += (double)partial[i];
    for (int off = 32; off > 0; off >>= 1)
        acc += __shfl_down(acc, off, 64);
    __shared__ double smem[BLOCK_SIZE / 64];
    const int lane = threadIdx.x & 63;
    const int wid = threadIdx.x >> 6;
    if (lane == 0) smem[wid] = acc;
    __syncthreads();
    if (threadIdx.x == 0) {
        double s = 0.0;
        #pragma unroll
        for (int w = 0; w < BLOCK_SIZE / 64; ++w) s += smem[w];
        out[0] = (float)(s * (double)scale);
    }
}

extern "C" void kernel_launch(void* const* d_in, const int* in_sizes, int n_in,
                              void* d_out, int out_size, void* d_ws, size_t ws_size,
                              hipStream_t stream) {
    const float* predict = (const float*)d_in[0];
    const float* target  = (const float*)d_in[1];
    float* out = (float*)d_out;
    float* partial = (float*)d_ws;

    const int n = in_sizes[0];      // 64*3*17*4096 = 13,369,344
    const int n4 = n / 4;           // divisible (4096 % 4 == 0)
    // divisor = bs*actionlen*seqlen = n / ddim = n / 3
    const float scale = 3.0f / (float)n;

    int blocks = (n4 + BLOCK_SIZE - 1) / BLOCK_SIZE;
    if (blocks > NUM_BLOCKS) blocks = NUM_BLOCKS;

    pm_mse_partial<<<blocks, BLOCK_SIZE, 0, stream>>>(
        (const float4*)predict, (const float4*)target, partial, n4);
    pm_mse_final<<<1, BLOCK_SIZE, 0, stream>>>(partial, blocks, out, scale);
}

// Round 2
// 122.025 us; speedup vs baseline: 1.0131x; 1.0131x over previous
//
#include <hip/hip_runtime.h>

// predict/target: fp32, shape (64, 3, 17, 4096)
// loss = sum((t-p)^2 * w[c]) / (bs*actionlen*seqlen),  w = {1, 1, 75825}
//
// Stage 1: fully-unrolled (8 iters, no bounds check) float4 grid-stride
//          reduction -> per-block partials in d_ws. 16 independent
//          global_load_dwordx4 in flight per thread for max MLP.
// Stage 2: single block reduces partials, scales, writes d_out[0].

#define BLOCK_SIZE 256
#define ITERS 8
#define VEC_PER_CHAN 17408   // (17*4096)/4 : float4-groups per channel segment
#define W2 75825.0f          // MAXLEN

__device__ __forceinline__ float blockReduce(float acc, float* smem) {
    for (int off = 32; off > 0; off >>= 1)
        acc += __shfl_down(acc, off, 64);
    const int lane = threadIdx.x & 63;
    const int wid = threadIdx.x >> 6;
    if (lane == 0) smem[wid] = acc;
    __syncthreads();
    float s = 0.0f;
    if (threadIdx.x == 0) {
        #pragma unroll
        for (int w = 0; w < BLOCK_SIZE / 64; ++w) s += smem[w];
    }
    return s;
}

// exact kernel: grid covers n4 exactly, no bounds checks, full unroll
__global__ __launch_bounds__(BLOCK_SIZE) void pm_mse_partial_exact(
    const float4* __restrict__ p, const float4* __restrict__ t,
    float* __restrict__ partial, int stride /* total threads */) {
    const int tid = blockIdx.x * BLOCK_SIZE + threadIdx.x;

    float4 a[ITERS], b[ITERS];
    #pragma unroll
    for (int k = 0; k < ITERS; ++k) {
        int i = tid + k * stride;
        a[k] = p[i];
        b[k] = t[i];
    }
    float acc = 0.0f;
    #pragma unroll
    for (int k = 0; k < ITERS; ++k) {
        int i = tid + k * stride;
        float dx = b[k].x - a[k].x;
        float dy = b[k].y - a[k].y;
        float dz = b[k].z - a[k].z;
        float dw = b[k].w - a[k].w;
        float s = dx * dx + dy * dy + dz * dz + dw * dw;
        int c = (i / VEC_PER_CHAN) % 3;   // vec4 never straddles a channel
        acc += (c == 2) ? s * W2 : s;
    }

    __shared__ float smem[BLOCK_SIZE / 64];
    float s = blockReduce(acc, smem);
    if (threadIdx.x == 0) partial[blockIdx.x] = s;
}

// generic fallback (any n4)
__global__ __launch_bounds__(BLOCK_SIZE) void pm_mse_partial_generic(
    const float4* __restrict__ p, const float4* __restrict__ t,
    float* __restrict__ partial, int n4) {
    float acc = 0.0f;
    const int stride = gridDim.x * blockDim.x;
    for (int i = blockIdx.x * blockDim.x + threadIdx.x; i < n4; i += stride) {
        float4 a = p[i];
        float4 b = t[i];
        float dx = b.x - a.x;
        float dy = b.y - a.y;
        float dz = b.z - a.z;
        float dw = b.w - a.w;
        float s = dx * dx + dy * dy + dz * dz + dw * dw;
        int c = (i / VEC_PER_CHAN) % 3;
        acc += (c == 2) ? s * W2 : s;
    }
    __shared__ float smem[BLOCK_SIZE / 64];
    float s = blockReduce(acc, smem);
    if (threadIdx.x == 0) partial[blockIdx.x] = s;
}

__global__ __launch_bounds__(BLOCK_SIZE) void pm_mse_final(
    const float* __restrict__ partial, int nblocks, float* __restrict__ out,
    float scale) {
    double acc = 0.0;
    for (int i = threadIdx.x; i < nblocks; i += blockDim.x)
        acc += (double)partial[i];
    for (int off = 32; off > 0; off >>= 1)
        acc += __shfl_down(acc, off, 64);
    __shared__ double smem[BLOCK_SIZE / 64];
    const int lane = threadIdx.x & 63;
    const int wid = threadIdx.x >> 6;
    if (lane == 0) smem[wid] = acc;
    __syncthreads();
    if (threadIdx.x == 0) {
        double s = 0.0;
        #pragma unroll
        for (int w = 0; w < BLOCK_SIZE / 64; ++w) s += smem[w];
        out[0] = (float)(s * (double)scale);
    }
}

extern "C" void kernel_launch(void* const* d_in, const int* in_sizes, int n_in,
                              void* d_out, int out_size, void* d_ws, size_t ws_size,
                              hipStream_t stream) {
    const float* predict = (const float*)d_in[0];
    const float* target  = (const float*)d_in[1];
    float* out = (float*)d_out;
    float* partial = (float*)d_ws;

    const int n = in_sizes[0];      // 64*3*17*4096 = 13,369,344
    const int n4 = n / 4;           // 3,342,336 = 256 * 8 * 1632
    const float scale = 3.0f / (float)n;  // divisor = n / ddim

    const int chunk = BLOCK_SIZE * ITERS;
    if (n4 % chunk == 0) {
        const int blocks = n4 / chunk;               // 1632
        const int stride = blocks * BLOCK_SIZE;      // 417,792
        pm_mse_partial_exact<<<blocks, BLOCK_SIZE, 0, stream>>>(
            (const float4*)predict, (const float4*)target, partial, stride);
        pm_mse_final<<<1, BLOCK_SIZE, 0, stream>>>(partial, blocks, out, scale);
    } else {
        int blocks = (n4 + BLOCK_SIZE - 1) / BLOCK_SIZE;
        if (blocks > 2048) blocks = 2048;
        pm_mse_partial_generic<<<blocks, BLOCK_SIZE, 0, stream>>>(
            (const float4*)predict, (const float4*)target, partial, n4);
        pm_mse_final<<<1, BLOCK_SIZE, 0, stream>>>(partial, blocks, out, scale);
    }
}